// Round 13
// baseline (49.584 us; speedup 1.0000x reference)
//
#include <hip/hip_runtime.h>
#include <hip/hip_bf16.h>
#include <math.h>

#define B_   8
#define T_   2048
#define C_   1024
#define HS_  64
#define MTOT (B_*T_)          // 16384 rows

typedef __attribute__((ext_vector_type(8))) short bf16x8;           // MFMA A/B
typedef __attribute__((ext_vector_type(4))) float f32x4;            // MFMA C/D
typedef __attribute__((ext_vector_type(8))) unsigned short u16x8;   // 16B store

static __device__ __forceinline__ unsigned short f2bf(float f) {
    __hip_bfloat16 h = __float2bfloat16(f);
    return *reinterpret_cast<unsigned short*>(&h);
}

// ---------------------------------------------------------------------------
// Kernel 0: cast W -> bf16, TRANSPOSED + concatenated: Wt[n=192][k=1024].
// Q section pre-scaled by C^-0.5 * log2(e)  ->  softmax runs in exp2 domain.
// ---------------------------------------------------------------------------
__global__ __launch_bounds__(256) void cast_w_kernel(
    const float* __restrict__ Wq, const float* __restrict__ Wk,
    const float* __restrict__ Wv, unsigned short* __restrict__ Wt)
{
    const int tid = threadIdx.x;
    const int col = tid & 63;
    const int kc  = tid >> 6;                     // 0..3
    const int mat = blockIdx.y;
    const int k0  = (blockIdx.x * 4 + kc) * 8;
    const float* __restrict__ W = (mat == 0) ? Wq : (mat == 1) ? Wk : Wv;
    const float s = (mat == 0) ? 0.03125f * 1.44269504f : 1.0f;  // C^-0.5 * log2e

    u16x8 o;
#pragma unroll
    for (int i = 0; i < 8; ++i)
        o[i] = f2bf(W[(size_t)(k0 + i) * HS_ + col] * s);
    *(u16x8*)&Wt[(size_t)(mat * 64 + col) * C_ + k0] = o;
}

// ---------------------------------------------------------------------------
// Kernel 1: FUSED QKV projection via bf16 MFMA (r11 config: depth-2 A
// prefetch — current best, unchanged).
// ---------------------------------------------------------------------------
__global__ __launch_bounds__(512) void proj_gemm(
    const float* __restrict__ x, const unsigned short* __restrict__ Wt,
    unsigned short* __restrict__ qbf, unsigned short* __restrict__ kbf,
    unsigned short* __restrict__ vtbf)
{
    __shared__ unsigned short Als[2][64][72];    // A tile [row][k]
    __shared__ unsigned short Bls[2][192][72];   // B tile [n=mat*64+col][k]

    const int tid  = threadIdx.x;
    const int lane = tid & 63;
    const int wv   = tid >> 6;        // 0..7
    const int wr   = wv & 1;          // row half (32)
    const int cg   = wv >> 1;         // col group: cols cg*48 .. +47
    const int g    = lane >> 4;
    const int n15  = lane & 15;
    const int g4   = g * 4;
    const int m0   = blockIdx.x * 64;

    const int srow = tid >> 3;        // 0..63
    const int seg  = (tid & 7) * 8;
    const float* __restrict__ xrow = &x[(size_t)(m0 + srow) * C_ + seg];
    const unsigned short* __restrict__ wrow = &Wt[(size_t)srow * C_ + seg];

    f32x4 acc[2][3];
#pragma unroll
    for (int i = 0; i < 2; ++i)
#pragma unroll
        for (int j = 0; j < 3; ++j) acc[i][j] = (f32x4){0.f, 0.f, 0.f, 0.f};

    float4 a0[2], a1[2];              // A prefetch regsets (depth 2)
    int4   b0, b1, b2;                // B regs (depth 1)

#define PROJ_LOAD_A(KC, S)                                              \
    do {                                                                \
        a0[S] = *(const float4*)&xrow[(KC) * 64 + 0];                   \
        a1[S] = *(const float4*)&xrow[(KC) * 64 + 4];                   \
    } while (0)

#define PROJ_LOAD_B(KC)                                                 \
    do {                                                                \
        b0 = *(const int4*)&wrow[(KC) * 64];                            \
        b1 = *(const int4*)&wrow[(size_t)64  * C_ + (KC) * 64];        \
        b2 = *(const int4*)&wrow[(size_t)128 * C_ + (KC) * 64];        \
    } while (0)

#define PROJ_WRITE_A(BUF, S)                                            \
    do {                                                                \
        u16x8 v0;                                                       \
        v0[0]=f2bf(a0[S].x); v0[1]=f2bf(a0[S].y);                       \
        v0[2]=f2bf(a0[S].z); v0[3]=f2bf(a0[S].w);                       \
        v0[4]=f2bf(a1[S].x); v0[5]=f2bf(a1[S].y);                       \
        v0[6]=f2bf(a1[S].z); v0[7]=f2bf(a1[S].w);                       \
        *(u16x8*)&Als[BUF][srow][seg] = v0;                             \
    } while (0)

#define PROJ_WRITE_B(BUF)                                               \
    do {                                                                \
        *(int4*)&Bls[BUF][srow][seg]        = b0;                       \
        *(int4*)&Bls[BUF][srow + 64][seg]   = b1;                       \
        *(int4*)&Bls[BUF][srow + 128][seg]  = b2;                       \
    } while (0)

    PROJ_LOAD_A(0, 0);
    PROJ_LOAD_B(0);
    PROJ_WRITE_A(0, 0);
    PROJ_WRITE_B(0);
    PROJ_LOAD_A(1, 1);
    __syncthreads();

    const int NK = C_ / 64;           // 16
    for (int kc = 0; kc < NK; ++kc) {
        const int cur = kc & 1;
        const int ka  = (kc + 2 < NK) ? kc + 2 : NK - 1;   // A: depth 2
        const int kb  = (kc + 1 < NK) ? kc + 1 : NK - 1;   // B: depth 1
        PROJ_LOAD_A(ka, kc & 1);
        PROJ_LOAD_B(kb);

#pragma unroll
        for (int kk = 0; kk < 2; ++kk) {
            bf16x8 fa0 = *(const bf16x8*)&Als[cur][wr * 32 + n15][kk * 32 + g * 8];
            bf16x8 fa1 = *(const bf16x8*)&Als[cur][wr * 32 + 16 + n15][kk * 32 + g * 8];
            bf16x8 fb0 = *(const bf16x8*)&Bls[cur][cg * 48 + n15][kk * 32 + g * 8];
            bf16x8 fb1 = *(const bf16x8*)&Bls[cur][cg * 48 + 16 + n15][kk * 32 + g * 8];
            bf16x8 fb2 = *(const bf16x8*)&Bls[cur][cg * 48 + 32 + n15][kk * 32 + g * 8];
            acc[0][0] = __builtin_amdgcn_mfma_f32_16x16x32_bf16(fa0, fb0, acc[0][0], 0, 0, 0);
            acc[0][1] = __builtin_amdgcn_mfma_f32_16x16x32_bf16(fa0, fb1, acc[0][1], 0, 0, 0);
            acc[0][2] = __builtin_amdgcn_mfma_f32_16x16x32_bf16(fa0, fb2, acc[0][2], 0, 0, 0);
            acc[1][0] = __builtin_amdgcn_mfma_f32_16x16x32_bf16(fa1, fb0, acc[1][0], 0, 0, 0);
            acc[1][1] = __builtin_amdgcn_mfma_f32_16x16x32_bf16(fa1, fb1, acc[1][1], 0, 0, 0);
            acc[1][2] = __builtin_amdgcn_mfma_f32_16x16x32_bf16(fa1, fb2, acc[1][2], 0, 0, 0);
        }

        if (kc + 1 < NK) {
            __syncthreads();
            PROJ_WRITE_A(cur ^ 1, (kc + 1) & 1);
            PROJ_WRITE_B(cur ^ 1);
            __syncthreads();
        }
    }
#undef PROJ_LOAD_A
#undef PROJ_LOAD_B
#undef PROJ_WRITE_A
#undef PROJ_WRITE_B

    // ---- epilogue: stage C tile in LDS, then coalesced stores ----
    __syncthreads();
    unsigned short* Cqk = &Als[0][0][0];   // [64][136]
    unsigned short* Vtr = &Bls[0][0][0];   // [64(hs)][72]

#pragma unroll
    for (int i = 0; i < 2; ++i)
#pragma unroll
        for (int j = 0; j < 3; ++j) {
            const int gcol = cg * 48 + j * 16 + n15;
            const int row0 = wr * 32 + i * 16 + g4;
            if (gcol < 128) {
#pragma unroll
                for (int r = 0; r < 4; ++r)
                    Cqk[(size_t)(row0 + r) * 136 + gcol] = f2bf(acc[i][j][r]);
            } else {
                ushort4 o;
                o.x = f2bf(acc[i][j][0]); o.y = f2bf(acc[i][j][1]);
                o.z = f2bf(acc[i][j][2]); o.w = f2bf(acc[i][j][3]);
                *(ushort4*)&Vtr[(size_t)(gcol - 128) * 72 + row0] = o;
            }
        }
    __syncthreads();

#pragma unroll
    for (int p = 0; p < 2; ++p) {
        const int flat = tid + p * 512;
        const int mat  = flat >> 9;          // 0=q, 1=k
        const int r64  = (flat >> 3) & 63;
        const int sg   = (flat & 7) * 8;
        unsigned short* __restrict__ dst = mat ? kbf : qbf;
        *(int4*)&dst[(size_t)(m0 + r64) * HS_ + sg] =
            *(const int4*)&Cqk[(size_t)r64 * 136 + mat * 64 + sg];
    }
    {
        const int b  = m0 >> 11;
        const int t0 = m0 & 2047;
        const int hs = tid >> 3;             // 0..63
        *(int4*)&vtbf[((size_t)b * HS_ + hs) * T_ + t0 + seg] =
            *(const int4*)&Vtr[(size_t)hs * 72 + seg];
    }
}

// ---------------------------------------------------------------------------
// Kernel 2: causal flash attention, bf16 MFMA.  NEW: 3-slot LDS rotation ->
// ONE barrier per iteration (write next-tile regs right after the barrier,
// compute current slot, issue loads 2 tiles ahead).  Slot safety: readers of
// slot s (iter j-2) are 2 barriers before its re-write (top of iter j); a
// write (top of j) is 1 barrier before its readers (iter j+1).  110.6 KB LDS
// -> 1 block/CU (r8 showed co-residency ~ null).  Balance via the validated
// two-pass (x, 63-x) pairing, grid (32,8).  Compute/softmax/merge = r11
// verbatim (exp2 domain + defer-max).
// ---------------------------------------------------------------------------
__global__ __launch_bounds__(512) void attn_kernel(
    const unsigned short* __restrict__ qbf,
    const unsigned short* __restrict__ kbf,
    const unsigned short* __restrict__ vtbf,
    float* __restrict__ y)
{
    __shared__ unsigned short Ksl[3][2][64][72];   // [slot][grp][key][hs]
    __shared__ unsigned short Vsl[3][2][64][72];   // [slot][grp][hs][key]

    const int tid  = threadIdx.x;
    const int lane = tid & 63;
    const int wv   = tid >> 6;        // 0..7
    const int rg   = wv & 1;          // query 16-group
    const int h    = (wv >> 1) & 1;   // KV 32-half within tile
    const int tp   = wv >> 2;         // tile parity group
    const int g    = lane >> 4;
    const int n15  = lane & 15;
    const int g4   = g * 4;
    const int b    = blockIdx.y;
    const size_t qkoff = (size_t)b * T_ * HS_;
    const size_t voff  = (size_t)b * HS_ * T_;

    const int sgrp = tid >> 8;        // staging group == its waves' tp
    const int st   = tid & 255;
    const int srow = st >> 3;         // 0..31
    const int soff = (st & 7) * 8;

    const unsigned short* __restrict__ kgb = &kbf[qkoff];
    const unsigned short* __restrict__ vgb = &vtbf[voff];

#define ATTN_LOADSET(K0, K1, V0, V1, TIX)                                   \
    do {                                                                    \
        K0 = *(const int4*)&kgb[(size_t)((TIX) * 64 + srow) * HS_ + soff];  \
        K1 = *(const int4*)&kgb[(size_t)((TIX) * 64 + srow + 32) * HS_ + soff]; \
        V0 = *(const int4*)&vgb[(size_t)srow * T_ + (TIX) * 64 + soff];     \
        V1 = *(const int4*)&vgb[(size_t)(srow + 32) * T_ + (TIX) * 64 + soff]; \
    } while (0)

#define ATTN_WRITESET(K0, K1, V0, V1, SLOT)                                 \
    do {                                                                    \
        *(int4*)&Ksl[SLOT][sgrp][srow][soff]      = K0;                     \
        *(int4*)&Ksl[SLOT][sgrp][srow + 32][soff] = K1;                     \
        *(int4*)&Vsl[SLOT][sgrp][srow][soff]      = V0;                     \
        *(int4*)&Vsl[SLOT][sgrp][srow + 32][soff] = V1;                     \
    } while (0)

#define ATTN_COMPUTE(SC)                                                    \
    do {                                                                    \
        const int k0  = kt * 64;                                            \
        const int ks0 = h * 32;                                             \
        f32x4 st0 = {0.f,0.f,0.f,0.f}, st1 = st0;                           \
        {                                                                   \
            bf16x8 ka;                                                      \
            ka  = *(const bf16x8*)&Ksl[SC][tp][ks0 + n15][g * 8];           \
            st0 = __builtin_amdgcn_mfma_f32_16x16x32_bf16(ka, qf0, st0, 0, 0, 0); \
            ka  = *(const bf16x8*)&Ksl[SC][tp][ks0 + n15][g * 8 + 32];      \
            st0 = __builtin_amdgcn_mfma_f32_16x16x32_bf16(ka, qf1, st0, 0, 0, 0); \
            ka  = *(const bf16x8*)&Ksl[SC][tp][ks0 + 16 + n15][g * 8];      \
            st1 = __builtin_amdgcn_mfma_f32_16x16x32_bf16(ka, qf0, st1, 0, 0, 0); \
            ka  = *(const bf16x8*)&Ksl[SC][tp][ks0 + 16 + n15][g * 8 + 32]; \
            st1 = __builtin_amdgcn_mfma_f32_16x16x32_bf16(ka, qf1, st1, 0, 0, 0); \
        }                                                                   \
        const int kb = k0 + h * 32 + g4;                                    \
        _Pragma("unroll")                                                   \
        for (int r = 0; r < 4; ++r) {                                       \
            if (kb + r      > qrow) st0[r] = -INFINITY;                     \
            if (kb + 16 + r > qrow) st1[r] = -INFINITY;                     \
        }                                                                   \
        float mloc = fmaxf(fmaxf(st0[0], st0[1]), fmaxf(st0[2], st0[3]));   \
        mloc = fmaxf(mloc, fmaxf(fmaxf(st1[0], st1[1]), fmaxf(st1[2], st1[3]))); \
        mloc = fmaxf(mloc, __shfl_xor(mloc, 16));                           \
        mloc = fmaxf(mloc, __shfl_xor(mloc, 32));                           \
        if (!__all(mloc <= mrow + 8.0f)) {                                  \
            float mnew  = fmaxf(mrow, mloc);                                \
            float corr  = exp2f(mrow - fmaxf(mnew, -1e30f));                \
            _Pragma("unroll")                                               \
            for (int r = 0; r < 4; ++r) {                                   \
                float cr = __shfl(corr, g4 + r);                            \
                o0[r] *= cr; o1[r] *= cr; o2[r] *= cr; o3[r] *= cr;         \
            }                                                               \
            lrow *= corr;                                                   \
            mrow  = mnew;                                                   \
        }                                                                   \
        const float mb = fmaxf(mrow, -1e30f);                               \
        float p[8];                                                         \
        float psum = 0.f;                                                   \
        _Pragma("unroll")                                                   \
        for (int r = 0; r < 4; ++r) {                                       \
            p[r]     = exp2f(st0[r] - mb);                                  \
            p[4 + r] = exp2f(st1[r] - mb);                                  \
            psum += p[r] + p[4 + r];                                        \
        }                                                                   \
        psum += __shfl_xor(psum, 16);                                       \
        psum += __shfl_xor(psum, 32);                                       \
        lrow += psum;                                                       \
        bf16x8 pa;                                                          \
        _Pragma("unroll")                                                   \
        for (int r = 0; r < 4; ++r) {                                       \
            pa[r]     = (short)f2bf(p[r]);                                  \
            pa[4 + r] = (short)f2bf(p[4 + r]);                              \
        }                                                                   \
        const int kvo = h * 32;                                             \
        {                                                                   \
            ushort4 lo, hi; bf16x8 vb;                                      \
            _Pragma("unroll")                                               \
            for (int nt = 0; nt < 4; ++nt) {                                \
                lo = *(const ushort4*)&Vsl[SC][tp][nt * 16 + n15][kvo + g4];      \
                hi = *(const ushort4*)&Vsl[SC][tp][nt * 16 + n15][kvo + 16 + g4]; \
                vb[0] = (short)lo.x; vb[1] = (short)lo.y;                   \
                vb[2] = (short)lo.z; vb[3] = (short)lo.w;                   \
                vb[4] = (short)hi.x; vb[5] = (short)hi.y;                   \
                vb[6] = (short)hi.z; vb[7] = (short)hi.w;                   \
                if (nt == 0) o0 = __builtin_amdgcn_mfma_f32_16x16x32_bf16(pa, vb, o0, 0, 0, 0); \
                if (nt == 1) o1 = __builtin_amdgcn_mfma_f32_16x16x32_bf16(pa, vb, o1, 0, 0, 0); \
                if (nt == 2) o2 = __builtin_amdgcn_mfma_f32_16x16x32_bf16(pa, vb, o2, 0, 0, 0); \
                if (nt == 3) o3 = __builtin_amdgcn_mfma_f32_16x16x32_bf16(pa, vb, o3, 0, 0, 0); \
            }                                                               \
        }                                                                   \
    } while (0)

    for (int pass = 0; pass < 2; ++pass) {
        const int qbi  = pass ? (63 - (int)blockIdx.x) : (int)blockIdx.x;
        const int q0   = qbi * 32;
        const int qq0  = q0 + rg * 16;
        const int qrow = qq0 + n15;
        const int nkt  = (qbi >> 1) + 1;
        const int J    = (nkt + 1) >> 1;

        bf16x8 qf0 = *(const bf16x8*)&qbf[qkoff + (size_t)qrow * HS_ + g * 8];
        bf16x8 qf1 = *(const bf16x8*)&qbf[qkoff + (size_t)qrow * HS_ + g * 8 + 32];

        f32x4 o0 = {0.f,0.f,0.f,0.f}, o1 = o0, o2 = o0, o3 = o0;
        float mrow = -INFINITY, lrow = 0.f;

        int4 kA0, kA1, vA0, vA1;      // staging regset A
        int4 kB0, kB1, vB0, vB1;      // staging regset B

        // prologue: setA = iter-0 tiles (tile sgrp, clamped)
        {
            int tix = (sgrp < nkt) ? sgrp : nkt - 1;
            ATTN_LOADSET(kA0, kA1, vA0, vA1, tix);
        }
        __syncthreads();               // pass-top: prior pass done with LDS
        ATTN_WRITESET(kA0, kA1, vA0, vA1, 0);
        // setB = iter-1 tiles (tile 2+sgrp, clamped)
        {
            int tix = 2 + sgrp; if (tix > nkt - 1) tix = nkt - 1;
            ATTN_LOADSET(kB0, kB1, vB0, vB1, tix);
        }
        __syncthreads();               // slot 0 visible

        int j = 0;
        while (true) {
            // ---- even-phase iter: write setB (iter j+1), load setA (iter j+2)
            {
                if (j + 1 < J) {
                    const int sN = (j + 1) % 3;
                    ATTN_WRITESET(kB0, kB1, vB0, vB1, sN);
                }
                {
                    int tix = 2 * (j + 2) + sgrp;
                    if (tix > nkt - 1) tix = nkt - 1;
                    ATTN_LOADSET(kA0, kA1, vA0, vA1, tix);
                }
                const int kt = 2 * j + tp;
                const int sC = j % 3;
                if (kt < nkt) ATTN_COMPUTE(sC);
                __syncthreads();
            }
            if (++j >= J) break;
            // ---- odd-phase iter: write setA (iter j+1), load setB (iter j+2)
            {
                if (j + 1 < J) {
                    const int sN = (j + 1) % 3;
                    ATTN_WRITESET(kA0, kA1, vA0, vA1, sN);
                }
                {
                    int tix = 2 * (j + 2) + sgrp;
                    if (tix > nkt - 1) tix = nkt - 1;
                    ATTN_LOADSET(kB0, kB1, vB0, vB1, tix);
                }
                const int kt = 2 * j + tp;
                const int sC = j % 3;
                if (kt < nkt) ATTN_COMPUTE(sC);
                __syncthreads();
            }
            if (++j >= J) break;
        }

        // ---- 4-way merge (partials pid = tp*2+h), exp2 domain ----
        // loop's final barrier orders all compute before FS reuse
        float* FS = (float*)&Ksl[0][0][0][0];     // scratch (26.9 KB < 55 KB)
        const int pid = (tp << 1) | h;
        if (pid != 0) {
            float* Ob = FS + (pid - 1) * 2176 + rg * 1088;
#pragma unroll
            for (int r = 0; r < 4; ++r) {
                Ob[(g4 + r) * 68 +  0 + n15] = o0[r];
                Ob[(g4 + r) * 68 + 16 + n15] = o1[r];
                Ob[(g4 + r) * 68 + 32 + n15] = o2[r];
                Ob[(g4 + r) * 68 + 48 + n15] = o3[r];
            }
            if (g == 0) {
                FS[6528 + (pid - 1) * 32 + rg * 16 + n15] = mrow;
                FS[6624 + (pid - 1) * 32 + rg * 16 + n15] = lrow;
            }
        }
        __syncthreads();
        if (pid == 0) {
            float m1 = FS[6528 +  0 + rg * 16 + n15];
            float m2 = FS[6528 + 32 + rg * 16 + n15];
            float m3 = FS[6528 + 64 + rg * 16 + n15];
            float l1 = FS[6624 +  0 + rg * 16 + n15];
            float l2 = FS[6624 + 32 + rg * 16 + n15];
            float l3 = FS[6624 + 64 + rg * 16 + n15];
            float mm = fmaxf(fmaxf(mrow, m1), fmaxf(m2, m3));   // finite: pid0 covers tile 0
            float f0 = exp2f(mrow - mm);
            float f1 = exp2f(m1 - mm);
            float f2 = exp2f(m2 - mm);
            float f3 = exp2f(m3 - mm);
            float invl = 1.0f / (lrow * f0 + l1 * f1 + l2 * f2 + l3 * f3);
            const float* O1s = FS;
            const float* O2s = FS + 2176;
            const float* O3s = FS + 4352;
#pragma unroll
            for (int r = 0; r < 4; ++r) {
                float fr0 = __shfl(f0, g4 + r);
                float fr1 = __shfl(f1, g4 + r);
                float fr2 = __shfl(f2, g4 + r);
                float fr3 = __shfl(f3, g4 + r);
                float ir  = __shfl(invl, g4 + r);
                const int base = rg * 1088 + (g4 + r) * 68 + n15;
                float* yr = &y[((size_t)b * T_ + qq0 + g4 + r) * HS_];
                yr[ 0 + n15] = (o0[r] * fr0 + O1s[base]      * fr1 +
                                O2s[base]      * fr2 + O3s[base]      * fr3) * ir;
                yr[16 + n15] = (o1[r] * fr0 + O1s[base + 16] * fr1 +
                                O2s[base + 16] * fr2 + O3s[base + 16] * fr3) * ir;
                yr[32 + n15] = (o2[r] * fr0 + O1s[base + 32] * fr1 +
                                O2s[base + 32] * fr2 + O3s[base + 32] * fr3) * ir;
                yr[48 + n15] = (o3[r] * fr0 + O1s[base + 48] * fr1 +
                                O2s[base + 48] * fr2 + O3s[base + 48] * fr3) * ir;
            }
        }
    }
#undef ATTN_LOADSET
#undef ATTN_WRITESET
#undef ATTN_COMPUTE
}

extern "C" void kernel_launch(void* const* d_in, const int* in_sizes, int n_in,
                              void* d_out, int out_size, void* d_ws, size_t ws_size,
                              hipStream_t stream)
{
    const float* x  = (const float*)d_in[0];
    const float* Wq = (const float*)d_in[1];
    const float* Wk = (const float*)d_in[2];
    const float* Wv = (const float*)d_in[3];

    unsigned short* qbf  = (unsigned short*)d_ws;                 // [B,T,64] bf16 (prescaled, log2e)
    unsigned short* kbf  = qbf + (size_t)MTOT * HS_;              // [B,T,64] bf16
    unsigned short* vtbf = kbf + (size_t)MTOT * HS_;              // [B,64,T] bf16
    unsigned short* Wt   = vtbf + (size_t)MTOT * HS_;             // [192][1024] bf16

    cast_w_kernel<<<dim3(32, 3), 256, 0, stream>>>(Wq, Wk, Wv, Wt);
    proj_gemm<<<256, 512, 0, stream>>>(x, Wt, qbf, kbf, vtbf);
    attn_kernel<<<dim3(32, B_), 512, 0, stream>>>(qbf, kbf, vtbf, (float*)d_out);
}